// Round 5
// baseline (849.725 us; speedup 1.0000x reference)
//
#include <hip/hip_runtime.h>
#include <hip/hip_bf16.h>

// GAT forward: N=8192, IN=512, HID=256, OUT=64.
// exp-factorization + monotonicity: w_ij = A_ij * max( e^{s1_i} e^{s2_j},
//                                                      e^{0.2 s1_i} e^{0.2 s2_j} )
// v4.1: A bit-packed by a dedicated streaming kernel (268MB -> 8.4MB, ~BW-bound);
// k_attn_pk reads only the L2-resident bitmask (preloaded to regs) -> no HBM
// latency in the MFMA loop. Fallback to v3 k_attn if ws_size < 21.7MB.

typedef float f32x4 __attribute__((ext_vector_type(4)));
typedef short s16x8 __attribute__((ext_vector_type(8)));

#define NN 8192
#define INDIM 512
#define HIDD 256
#define OUTD 64

static __device__ __forceinline__ short f2bf(float x) {
    __hip_bfloat16 h = __float2bfloat16(x);
    return __builtin_bit_cast(short, h);
}

static __device__ __forceinline__ unsigned pk2bf(float a, float b) {
    unsigned ha = (unsigned)(unsigned short)f2bf(a);
    unsigned hb = (unsigned)(unsigned short)f2bf(b);
    return ha | (hb << 16);
}

static __device__ __forceinline__ void split_bf(float x, short& hi, short& lo) {
    short h = f2bf(x);
    unsigned int hb = ((unsigned int)(unsigned short)h) << 16;
    float hf = __builtin_bit_cast(float, hb);
    hi = h;
    lo = f2bf(x - hf);
}

// ---- prep: X (f32 [8192][512]) -> bf16-hi in A-frag-contiguous layout ---------------
__global__ void k_prepX(const float* __restrict__ X, short* __restrict__ XBhi) {
    int t = blockIdx.x * 256 + threadIdx.x;        // 4,194,304
    int r = t >> 9, k = t & 511;
    XBhi[(r >> 4) * 8192 + (k >> 3) * 128 + (r & 15) * 8 + (k & 7)] = f2bf(X[t]);
}

// ---- prep: W1 (f32 [512][256]) -> split hi/lo bf16 in B-frag-contiguous layout ------
__global__ void k_prepW(const float* __restrict__ W1,
                        short* __restrict__ WBhi, short* __restrict__ WBlo) {
    int t = blockIdx.x * 256 + threadIdx.x;        // 131,072
    int k = t >> 8, n = t & 255;
    short h, l; split_bf(W1[t], h, l);
    int idx = (n >> 4) * 8192 + (k >> 3) * 128 + (n & 15) * 8 + (k & 7);
    WBhi[idx] = h;
    WBlo[idx] = l;
}

// ---- prep: A (int32 [8192][8192]) -> 1 bit/edge bitmask (8.4 MB) --------------------
// Pure streaming: coalesced dword loads, __ballot across the wave, lane0 stores u64.
__global__ void __launch_bounds__(256) k_packA(const int* __restrict__ A,
                                               unsigned long long* __restrict__ Apk64) {
    const int tid = threadIdx.x;
    int f = blockIdx.x * 256 + tid;                // grid 2048 -> stride 524288
#pragma unroll 4
    for (int it = 0; it < 128; ++it) {
        int a = A[(size_t)f];
        unsigned long long m = __ballot(a > 0);
        if ((tid & 63) == 0) Apk64[f >> 6] = m;    // bit L <-> j = f0 + L (ascending)
        f += 524288;
    }
}

// ---- k_h1: H1 = X@W1 + b1 (Xhi x (Whi+Wlo), 2 MFMA) ---------------------------------
__global__ void __launch_bounds__(256, 2)
k_h1(const short* __restrict__ XBhi, const short* __restrict__ WBhi,
     const short* __restrict__ WBlo, const float* __restrict__ b1,
     const float* __restrict__ avec, unsigned short* __restrict__ H1TB,
     float* __restrict__ alw, float* __restrict__ bew, float* __restrict__ uvw) {
    __shared__ float s1p[4][16];
    __shared__ float s2p[4][16];
    const int tid = threadIdx.x;
    const int wn = tid >> 6, lane = tid & 63;
    const int q = lane >> 4, m16 = lane & 15;
    const int blk = blockIdx.x;

    f32x4 zero4 = {0.f, 0.f, 0.f, 0.f};
    f32x4 acc[4];
#pragma unroll
    for (int nt = 0; nt < 4; ++nt) acc[nt] = zero4;

    const short* xh = XBhi + blk * 8192 + q * 128 + m16 * 8;
    const short* wh = WBhi + wn * 4 * 8192 + q * 128 + m16 * 8;
    const short* wl = WBlo + wn * 4 * 8192 + q * 128 + m16 * 8;

    for (int c = 0; c < 16; ++c) {
        s16x8 ahi = *(const s16x8*)(xh + c * 512);
#pragma unroll
        for (int nt = 0; nt < 4; ++nt) {
            s16x8 bhi = *(const s16x8*)(wh + nt * 8192 + c * 512);
            s16x8 blo = *(const s16x8*)(wl + nt * 8192 + c * 512);
            acc[nt] = __builtin_amdgcn_mfma_f32_16x16x32_bf16(ahi, bhi, acc[nt], 0, 0, 0);
            acc[nt] = __builtin_amdgcn_mfma_f32_16x16x32_bf16(ahi, blo, acc[nt], 0, 0, 0);
        }
    }

    float p1[4] = {0.f, 0.f, 0.f, 0.f};
    float p2[4] = {0.f, 0.f, 0.f, 0.f};
#pragma unroll
    for (int nt = 0; nt < 4; ++nt) {
        const int col = wn * 64 + nt * 16 + m16;
        const float b1v = b1[col];
        const float a1v = avec[col];
        const float a2v = avec[HIDD + col];
        float v0 = acc[nt][0] + b1v;
        float v1 = acc[nt][1] + b1v;
        float v2 = acc[nt][2] + b1v;
        float v3 = acc[nt][3] + b1v;
        ushort4 us;
        us.x = (unsigned short)f2bf(v0);
        us.y = (unsigned short)f2bf(v1);
        us.z = (unsigned short)f2bf(v2);
        us.w = (unsigned short)f2bf(v3);
        const int idx = ((wn * 4 + nt) * 1024 + blk * 2 + (q >> 1)) * 128
                        + m16 * 8 + (q & 1) * 4;
        *(ushort4*)(H1TB + idx) = us;
        p1[0] += v0 * a1v; p1[1] += v1 * a1v; p1[2] += v2 * a1v; p1[3] += v3 * a1v;
        p2[0] += v0 * a2v; p2[1] += v1 * a2v; p2[2] += v2 * a2v; p2[3] += v3 * a2v;
    }
#pragma unroll
    for (int off = 1; off < 16; off <<= 1) {
#pragma unroll
        for (int r = 0; r < 4; ++r) {
            p1[r] += __shfl_xor(p1[r], off);
            p2[r] += __shfl_xor(p2[r], off);
        }
    }
    if (m16 == 0) {
#pragma unroll
        for (int r = 0; r < 4; ++r) {
            s1p[wn][q * 4 + r] = p1[r];
            s2p[wn][q * 4 + r] = p2[r];
        }
    }
    __syncthreads();
    if (tid < 16) {
        const int i = blk * 16 + tid;
        float s1 = s1p[0][tid] + s1p[1][tid] + s1p[2][tid] + s1p[3][tid];
        float s2 = s2p[0][tid] + s2p[1][tid] + s2p[2][tid] + s2p[3][tid];
        alw[i] = expf(s1);
        bew[i] = expf(0.2f * s1);
        uvw[2 * i]     = expf(s2);
        uvw[2 * i + 1] = expf(0.2f * s2);
    }
}

// ---- k_attn_pk: H2acc += W @ H1, Z += rowsum(W). Bitmask A in registers. ------------
// Grid 2048 = mb(256, 32 rows) x ks(8, 1024 j). Block 256 = 4 waves (wm2 x wn2):
// wave = 16 rows x 128 hid. A-window (32 words) preloaded as 8 uint4 -> no global
// A access in the loop; B-frags from L2 (512KB slice/XCD); uv L1-resident (8KB).
__global__ void __launch_bounds__(256, 4)
k_attn_pk(const unsigned int* __restrict__ Apk, const unsigned short* __restrict__ H1TB,
          const float* __restrict__ alw, const float* __restrict__ bew,
          const float* __restrict__ uvw,
          float* __restrict__ H2acc, float* __restrict__ Zw) {
    const int tid = threadIdx.x;
    const int wave = tid >> 6, lane = tid & 63;
    const int q = lane >> 4, m16 = lane & 15;
    const int wm = wave & 1, wn = wave >> 1;
    const int ks = blockIdx.x & 7;                 // XCD-aligned K-slice
    const int mb = blockIdx.x >> 3;
    const int row = mb * 32 + wm * 16 + m16;
    const float al = alw[row], be = bew[row];

    const uint4* aw4 = (const uint4*)(Apk + row * 256 + ks * 32);
    uint4 awin[8];
#pragma unroll
    for (int c = 0; c < 8; ++c) awin[c] = aw4[c];  // 8 independent loads up front

    const float* uvp = uvw + 2 * (ks * 1024 + q * 8);
    const unsigned short* Hp = H1TB
        + ((size_t)(wn * 8) * 1024 + ks * 128 + q) * 128 + m16 * 8;

    f32x4 zero4 = {0.f, 0.f, 0.f, 0.f};
    f32x4 acc[8];
#pragma unroll
    for (int nt = 0; nt < 8; ++nt) acc[nt] = zero4;
    float z = 0.f;

#pragma unroll
    for (int c = 0; c < 8; ++c) {
        unsigned int wds[4] = {awin[c].x, awin[c].y, awin[c].z, awin[c].w};
#pragma unroll
        for (int u = 0; u < 4; ++u) {
            const int t = c * 4 + u;
            const unsigned int byte = (wds[u] >> (q * 8)) & 0xFFu;  // this lane's 8 bits
            float4 uv0 = *(const float4*)(uvp + t * 64);
            float4 uv1 = *(const float4*)(uvp + t * 64 + 4);
            float4 uv2 = *(const float4*)(uvp + t * 64 + 8);
            float4 uv3 = *(const float4*)(uvp + t * 64 + 12);
            float w[8];
            w[0] = (byte & 1u)   ? fmaxf(al * uv0.x, be * uv0.y) : 0.f;
            w[1] = (byte & 2u)   ? fmaxf(al * uv0.z, be * uv0.w) : 0.f;
            w[2] = (byte & 4u)   ? fmaxf(al * uv1.x, be * uv1.y) : 0.f;
            w[3] = (byte & 8u)   ? fmaxf(al * uv1.z, be * uv1.w) : 0.f;
            w[4] = (byte & 16u)  ? fmaxf(al * uv2.x, be * uv2.y) : 0.f;
            w[5] = (byte & 32u)  ? fmaxf(al * uv2.z, be * uv2.w) : 0.f;
            w[6] = (byte & 64u)  ? fmaxf(al * uv3.x, be * uv3.y) : 0.f;
            w[7] = (byte & 128u) ? fmaxf(al * uv3.z, be * uv3.w) : 0.f;
            z += (w[0] + w[1] + w[2] + w[3]) + (w[4] + w[5] + w[6] + w[7]);
            int4 ai = {(int)pk2bf(w[0], w[1]), (int)pk2bf(w[2], w[3]),
                       (int)pk2bf(w[4], w[5]), (int)pk2bf(w[6], w[7])};
            s16x8 af = __builtin_bit_cast(s16x8, ai);
#pragma unroll
            for (int nt = 0; nt < 8; ++nt) {
                s16x8 bf = *(const s16x8*)(Hp + (size_t)nt * 131072 + t * 512);
                acc[nt] = __builtin_amdgcn_mfma_f32_16x16x32_bf16(af, bf, acc[nt], 0, 0, 0);
            }
        }
    }

    // Z row-sum: reduce over q (lane bits 4,5); wn==0 only (wn pair duplicates W).
    z += __shfl_xor(z, 16);
    z += __shfl_xor(z, 32);
    if (wn == 0 && q == 0) atomicAdd(&Zw[row], z);

    const int rowb = mb * 32 + wm * 16 + q * 4;
#pragma unroll
    for (int nt = 0; nt < 8; ++nt) {
        const int col = wn * 128 + nt * 16 + m16;
#pragma unroll
        for (int r = 0; r < 4; ++r)
            atomicAdd(&H2acc[(size_t)(rowb + r) * HIDD + col], acc[nt][r]);
    }
}

// ---- k_attn_raw (fallback, ws too small): round-3 version verbatim ------------------
__global__ void __launch_bounds__(256, 4)
k_attn_raw(const int* __restrict__ A, const unsigned short* __restrict__ H1TB,
           const float* __restrict__ alw, const float* __restrict__ bew,
           const float* __restrict__ uvw,
           float* __restrict__ H2acc, float* __restrict__ Zw) {
    const int tid = threadIdx.x;
    const int wn = tid >> 6, lane = tid & 63;
    const int q = lane >> 4, m16 = lane & 15;
    const int ks = blockIdx.x & 7;
    const int mb = blockIdx.x >> 3;
    const int row0 = mb * 32 + m16, row1 = row0 + 16;
    const float al0 = alw[row0], be0 = bew[row0];
    const float al1 = alw[row1], be1 = bew[row1];
    const int j0 = ks * 1024;

    const int* Ap0 = A + (size_t)row0 * NN + j0 + q * 8;
    const int* Ap1 = A + (size_t)row1 * NN + j0 + q * 8;
    const float* uvp = uvw + 2 * (j0 + q * 8);
    const unsigned short* Hp = H1TB + ((size_t)(wn * 4) * 1024 + ks * 128 + q) * 128 + m16 * 8;

    f32x4 zero4 = {0.f, 0.f, 0.f, 0.f};
    f32x4 acc[8];
#pragma unroll
    for (int i = 0; i < 8; ++i) acc[i] = zero4;
    float z0 = 0.f, z1 = 0.f;

    int4 a00 = *(const int4*)(Ap0);
    int4 a01 = *(const int4*)(Ap0 + 4);
    int4 a10 = *(const int4*)(Ap1);
    int4 a11 = *(const int4*)(Ap1 + 4);

    for (int t = 0; t < 32; ++t) {
        int4 n00, n01, n10, n11;
        if (t < 31) {
            n00 = *(const int4*)(Ap0 + 32);
            n01 = *(const int4*)(Ap0 + 36);
            n10 = *(const int4*)(Ap1 + 32);
            n11 = *(const int4*)(Ap1 + 36);
        }
        float4 uv0 = *(const float4*)(uvp);
        float4 uv1 = *(const float4*)(uvp + 4);
        float4 uv2 = *(const float4*)(uvp + 8);
        float4 uv3 = *(const float4*)(uvp + 12);

        float w0[8], w1[8];
        w0[0] = (a00.x > 0) ? fmaxf(al0 * uv0.x, be0 * uv0.y) : 0.f;
        w0[1] = (a00.y > 0) ? fmaxf(al0 * uv0.z, be0 * uv0.w) : 0.f;
        w0[2] = (a00.z > 0) ? fmaxf(al0 * uv1.x, be0 * uv1.y) : 0.f;
        w0[3] = (a00.w > 0) ? fmaxf(al0 * uv1.z, be0 * uv1.w) : 0.f;
        w0[4] = (a01.x > 0) ? fmaxf(al0 * uv2.x, be0 * uv2.y) : 0.f;
        w0[5] = (a01.y > 0) ? fmaxf(al0 * uv2.z, be0 * uv2.w) : 0.f;
        w0[6] = (a01.z > 0) ? fmaxf(al0 * uv3.x, be0 * uv3.y) : 0.f;
        w0[7] = (a01.w > 0) ? fmaxf(al0 * uv3.z, be0 * uv3.w) : 0.f;
        w1[0] = (a10.x > 0) ? fmaxf(al1 * uv0.x, be1 * uv0.y) : 0.f;
        w1[1] = (a10.y > 0) ? fmaxf(al1 * uv0.z, be1 * uv0.w) : 0.f;
        w1[2] = (a10.z > 0) ? fmaxf(al1 * uv1.x, be1 * uv1.y) : 0.f;
        w1[3] = (a10.w > 0) ? fmaxf(al1 * uv1.z, be1 * uv1.w) : 0.f;
        w1[4] = (a11.x > 0) ? fmaxf(al1 * uv2.x, be1 * uv2.y) : 0.f;
        w1[5] = (a11.y > 0) ? fmaxf(al1 * uv2.z, be1 * uv2.w) : 0.f;
        w1[6] = (a11.z > 0) ? fmaxf(al1 * uv3.x, be1 * uv3.y) : 0.f;
        w1[7] = (a11.w > 0) ? fmaxf(al1 * uv3.z, be1 * uv3.w) : 0.f;
        z0 += (w0[0] + w0[1] + w0[2] + w0[3]) + (w0[4] + w0[5] + w0[6] + w0[7]);
        z1 += (w1[0] + w1[1] + w1[2] + w1[3]) + (w1[4] + w1[5] + w1[6] + w1[7]);

        s16x8 af0, af1;
#pragma unroll
        for (int j = 0; j < 8; ++j) { af0[j] = f2bf(w0[j]); af1[j] = f2bf(w1[j]); }

#pragma unroll
        for (int nt = 0; nt < 4; ++nt) {
            s16x8 bf = *(const s16x8*)(Hp + (size_t)nt * 131072 + t * 512);
            acc[nt * 2 + 0] = __builtin_amdgcn_mfma_f32_16x16x32_bf16(af0, bf, acc[nt * 2 + 0], 0, 0, 0);
            acc[nt * 2 + 1] = __builtin_amdgcn_mfma_f32_16x16x32_bf16(af1, bf, acc[nt * 2 + 1], 0, 0, 0);
        }
        if (t < 31) { a00 = n00; a01 = n01; a10 = n10; a11 = n11; }
        Ap0 += 32; Ap1 += 32; uvp += 64;
    }

    z0 += __shfl_xor(z0, 16); z0 += __shfl_xor(z0, 32);
    z1 += __shfl_xor(z1, 16); z1 += __shfl_xor(z1, 32);
    if (wn == 0 && q == 0) {
        atomicAdd(&Zw[row0], z0);
        atomicAdd(&Zw[row1], z1);
    }

#pragma unroll
    for (int nt = 0; nt < 4; ++nt) {
        const int col = wn * 64 + nt * 16 + m16;
#pragma unroll
        for (int rg = 0; rg < 2; ++rg) {
            const int rowb = mb * 32 + rg * 16 + q * 4;
#pragma unroll
            for (int r = 0; r < 4; ++r)
                atomicAdd(&H2acc[(size_t)(rowb + r) * HIDD + col], acc[nt * 2 + rg][r]);
        }
    }
}

// ---- k_out: out = sigmoid((H2acc/Z) @ Omega + beta) ---------------------------------
__global__ void __launch_bounds__(256)
k_out(const float* __restrict__ H2acc, const float* __restrict__ Zw,
      const float* __restrict__ Omega, const float* __restrict__ beta,
      float* __restrict__ out) {
    __shared__ float om[HIDD * OUTD];  // 64 KB
    const int tid = threadIdx.x;
    for (int idx = tid; idx < HIDD * OUTD; idx += 256) om[idx] = Omega[idx];
    __syncthreads();
    const int wave = tid >> 6, o = tid & 63;
    const int i0 = blockIdx.x * 32 + wave * 8;
    float acc[8] = {0.f, 0.f, 0.f, 0.f, 0.f, 0.f, 0.f, 0.f};
    for (int c = 0; c < HIDD; c += 4) {
        const float o0 = om[(c + 0) * OUTD + o];
        const float o1 = om[(c + 1) * OUTD + o];
        const float o2 = om[(c + 2) * OUTD + o];
        const float o3 = om[(c + 3) * OUTD + o];
#pragma unroll
        for (int r = 0; r < 8; ++r) {
            float4 h = *(const float4*)(H2acc + (size_t)(i0 + r) * HIDD + c);
            acc[r] = fmaf(h.x, o0, fmaf(h.y, o1, fmaf(h.z, o2, fmaf(h.w, o3, acc[r]))));
        }
    }
    const float bv = beta[o];
#pragma unroll
    for (int r = 0; r < 8; ++r) {
        const float logit = acc[r] / Zw[i0 + r] + bv;
        out[(size_t)(i0 + r) * OUTD + o] = 1.0f / (1.0f + expf(-logit));
    }
}

extern "C" void kernel_launch(void* const* d_in, const int* in_sizes, int n_in,
                              void* d_out, int out_size, void* d_ws, size_t ws_size,
                              hipStream_t stream) {
    const float* X     = (const float*)d_in[0];
    const int*   A     = (const int*)d_in[1];
    const float* W1    = (const float*)d_in[2];
    const float* b1    = (const float*)d_in[3];
    const float* avec  = (const float*)d_in[4];
    const float* Omega = (const float*)d_in[5];
    const float* beta  = (const float*)d_in[6];
    float* out = (float*)d_out;
    char* ws = (char*)d_ws;

    if (ws_size >= 21659648ull) {
        // ---- primary layout (21.7 MB) ----
        unsigned short* H1TB = (unsigned short*)(ws + 0);   // 4,194,304
        float* Zw    = (float*)(ws + 4194304);              // 32,768
        float* H2acc = (float*)(ws + 4227072);              // 8,388,608 (end 12,615,680)
        short* XBhi  = (short*)(ws + 4194304);              // 8,388,608 alias (dead before memset)
        unsigned int* Apk = (unsigned int*)(ws + 12615680); // 8,388,608 (end 21,004,288)
        short* WBhi  = (short*)(ws + 21004288);             // 262,144
        short* WBlo  = (short*)(ws + 21266432);             // 262,144
        float* alw   = (float*)(ws + 21528576);             // 32,768
        float* bew   = (float*)(ws + 21561344);             // 32,768
        float* uvw   = (float*)(ws + 21594112);             // 65,536 (end 21,659,648)

        k_prepX<<<16384, 256, 0, stream>>>(X, XBhi);
        k_prepW<<<512, 256, 0, stream>>>(W1, WBhi, WBlo);
        k_h1<<<512, 256, 0, stream>>>(XBhi, WBhi, WBlo, b1, avec, H1TB, alw, bew, uvw);
        k_packA<<<2048, 256, 0, stream>>>(A, (unsigned long long*)Apk);
        (void)hipMemsetAsync(Zw, 0, 32768 + 8388608, stream);  // kills XBhi (already consumed)
        k_attn_pk<<<2048, 256, 0, stream>>>(Apk, H1TB, alw, bew, uvw, H2acc, Zw);
        k_out<<<256, 256, 0, stream>>>(H2acc, Zw, Omega, beta, out);
    } else {
        // ---- fallback: round-3 layout/path (13.3 MB) ----
        unsigned short* H1TB = (unsigned short*)(ws + 0);   // 4,194,304
        short* XBhi  = (short*)(ws + 4194304);              // 8,388,608 alias
        float* Zw    = (float*)(ws + 4194304);              // 32,768
        float* H2acc = (float*)(ws + 4227072);              // 8,388,608 (end 12,615,680)
        short* WBhi  = (short*)(ws + 12615680);             // 262,144
        short* WBlo  = (short*)(ws + 12877824);             // 262,144
        float* alw   = (float*)(ws + 13139968);             // 32,768
        float* bew   = (float*)(ws + 13172736);             // 32,768
        float* uvw   = (float*)(ws + 13205504);             // 65,536 (end 13,271,040)

        k_prepX<<<16384, 256, 0, stream>>>(X, XBhi);
        k_prepW<<<512, 256, 0, stream>>>(W1, WBhi, WBlo);
        k_h1<<<512, 256, 0, stream>>>(XBhi, WBhi, WBlo, b1, avec, H1TB, alw, bew, uvw);
        (void)hipMemsetAsync(Zw, 0, 32768 + 8388608, stream);
        k_attn_raw<<<2048, 256, 0, stream>>>(A, H1TB, alw, bew, uvw, H2acc, Zw);
        k_out<<<256, 256, 0, stream>>>(H2acc, Zw, Omega, beta, out);
    }
}

// Round 6
// 590.481 us; speedup vs baseline: 1.4390x; 1.4390x over previous
//
#include <hip/hip_runtime.h>
#include <hip/hip_bf16.h>

// GAT forward: N=8192, IN=512, HID=256, OUT=64.
// exp-factorization + monotonicity: w_ij = A_ij * max( e^{s1_i} e^{s2_j},
//                                                      e^{0.2 s1_i} e^{0.2 s2_j} )
// v6: NO cross-block atomics. Each (mb, ks) block writes a private partial H2/Z
// (plain stores); k_out sums ksn partials + normalizes + Omega matmul.
// A is bit-packed (268MB -> 8.4MB) by k_packA; k_attn streams only cached data.

typedef float f32x4 __attribute__((ext_vector_type(4)));
typedef short s16x8 __attribute__((ext_vector_type(8)));

#define NN 8192
#define INDIM 512
#define HIDD 256
#define OUTD 64

static __device__ __forceinline__ short f2bf(float x) {
    __hip_bfloat16 h = __float2bfloat16(x);
    return __builtin_bit_cast(short, h);
}

static __device__ __forceinline__ unsigned pk2bf(float a, float b) {
    unsigned ha = (unsigned)(unsigned short)f2bf(a);
    unsigned hb = (unsigned)(unsigned short)f2bf(b);
    return ha | (hb << 16);
}

static __device__ __forceinline__ void split_bf(float x, short& hi, short& lo) {
    short h = f2bf(x);
    unsigned int hb = ((unsigned int)(unsigned short)h) << 16;
    float hf = __builtin_bit_cast(float, hb);
    hi = h;
    lo = f2bf(x - hf);
}

// ---- prep: X (f32 [8192][512]) -> bf16-hi in A-frag-contiguous layout ---------------
__global__ void k_prepX(const float* __restrict__ X, short* __restrict__ XBhi) {
    int t = blockIdx.x * 256 + threadIdx.x;        // 4,194,304
    int r = t >> 9, k = t & 511;
    XBhi[(r >> 4) * 8192 + (k >> 3) * 128 + (r & 15) * 8 + (k & 7)] = f2bf(X[t]);
}

// ---- prep: W1 (f32 [512][256]) -> split hi/lo bf16 in B-frag-contiguous layout ------
__global__ void k_prepW(const float* __restrict__ W1,
                        short* __restrict__ WBhi, short* __restrict__ WBlo) {
    int t = blockIdx.x * 256 + threadIdx.x;        // 131,072
    int k = t >> 8, n = t & 255;
    short h, l; split_bf(W1[t], h, l);
    int idx = (n >> 4) * 8192 + (k >> 3) * 128 + (n & 15) * 8 + (k & 7);
    WBhi[idx] = h;
    WBlo[idx] = l;
}

// ---- prep: A (int32 [8192][8192]) -> 1 bit/edge bitmask (8.4 MB), HBM-bound ---------
__global__ void __launch_bounds__(256) k_packA(const int* __restrict__ A,
                                               unsigned long long* __restrict__ Apk64) {
    const int tid = threadIdx.x;
    int f = blockIdx.x * 256 + tid;                // grid 2048 -> stride 524288
#pragma unroll 4
    for (int it = 0; it < 128; ++it) {
        int a = A[(size_t)f];
        unsigned long long m = __ballot(a > 0);
        if ((tid & 63) == 0) Apk64[f >> 6] = m;    // bit L <-> j = f0 + L
        f += 524288;
    }
}

// ---- k_h1: H1 = X@W1 + b1 (Xhi x (Whi+Wlo), 2 MFMA) ---------------------------------
__global__ void __launch_bounds__(256, 2)
k_h1(const short* __restrict__ XBhi, const short* __restrict__ WBhi,
     const short* __restrict__ WBlo, const float* __restrict__ b1,
     const float* __restrict__ avec, unsigned short* __restrict__ H1TB,
     float* __restrict__ alw, float* __restrict__ bew, float* __restrict__ uvw) {
    __shared__ float s1p[4][16];
    __shared__ float s2p[4][16];
    const int tid = threadIdx.x;
    const int wn = tid >> 6, lane = tid & 63;
    const int q = lane >> 4, m16 = lane & 15;
    const int blk = blockIdx.x;

    f32x4 zero4 = {0.f, 0.f, 0.f, 0.f};
    f32x4 acc[4];
#pragma unroll
    for (int nt = 0; nt < 4; ++nt) acc[nt] = zero4;

    const short* xh = XBhi + blk * 8192 + q * 128 + m16 * 8;
    const short* wh = WBhi + wn * 4 * 8192 + q * 128 + m16 * 8;
    const short* wl = WBlo + wn * 4 * 8192 + q * 128 + m16 * 8;

    for (int c = 0; c < 16; ++c) {
        s16x8 ahi = *(const s16x8*)(xh + c * 512);
#pragma unroll
        for (int nt = 0; nt < 4; ++nt) {
            s16x8 bhi = *(const s16x8*)(wh + nt * 8192 + c * 512);
            s16x8 blo = *(const s16x8*)(wl + nt * 8192 + c * 512);
            acc[nt] = __builtin_amdgcn_mfma_f32_16x16x32_bf16(ahi, bhi, acc[nt], 0, 0, 0);
            acc[nt] = __builtin_amdgcn_mfma_f32_16x16x32_bf16(ahi, blo, acc[nt], 0, 0, 0);
        }
    }

    float p1[4] = {0.f, 0.f, 0.f, 0.f};
    float p2[4] = {0.f, 0.f, 0.f, 0.f};
#pragma unroll
    for (int nt = 0; nt < 4; ++nt) {
        const int col = wn * 64 + nt * 16 + m16;
        const float b1v = b1[col];
        const float a1v = avec[col];
        const float a2v = avec[HIDD + col];
        float v0 = acc[nt][0] + b1v;
        float v1 = acc[nt][1] + b1v;
        float v2 = acc[nt][2] + b1v;
        float v3 = acc[nt][3] + b1v;
        ushort4 us;
        us.x = (unsigned short)f2bf(v0);
        us.y = (unsigned short)f2bf(v1);
        us.z = (unsigned short)f2bf(v2);
        us.w = (unsigned short)f2bf(v3);
        const int idx = ((wn * 4 + nt) * 1024 + blk * 2 + (q >> 1)) * 128
                        + m16 * 8 + (q & 1) * 4;
        *(ushort4*)(H1TB + idx) = us;
        p1[0] += v0 * a1v; p1[1] += v1 * a1v; p1[2] += v2 * a1v; p1[3] += v3 * a1v;
        p2[0] += v0 * a2v; p2[1] += v1 * a2v; p2[2] += v2 * a2v; p2[3] += v3 * a2v;
    }
#pragma unroll
    for (int off = 1; off < 16; off <<= 1) {
#pragma unroll
        for (int r = 0; r < 4; ++r) {
            p1[r] += __shfl_xor(p1[r], off);
            p2[r] += __shfl_xor(p2[r], off);
        }
    }
    if (m16 == 0) {
#pragma unroll
        for (int r = 0; r < 4; ++r) {
            s1p[wn][q * 4 + r] = p1[r];
            s2p[wn][q * 4 + r] = p2[r];
        }
    }
    __syncthreads();
    if (tid < 16) {
        const int i = blk * 16 + tid;
        float s1 = s1p[0][tid] + s1p[1][tid] + s1p[2][tid] + s1p[3][tid];
        float s2 = s2p[0][tid] + s2p[1][tid] + s2p[2][tid] + s2p[3][tid];
        alw[i] = expf(s1);
        bew[i] = expf(0.2f * s1);
        uvw[2 * i]     = expf(s2);
        uvw[2 * i + 1] = expf(0.2f * s2);
    }
}

// ---- k_attn_ns: H2p[ks] = W @ H1 (partial), Zp[ks] = rowsum(W). NO atomics. ---------
// Grid 256*ksn: ks = blk & (ksn-1) (XCD-aligned), mb = blk >> kslog (32 rows).
// Block 256 = 4 waves (wn4): wave = 32 rows (rg2) x 64 hid (nt4).
__global__ void __launch_bounds__(256, 3)
k_attn_ns(const unsigned int* __restrict__ Apk, const unsigned short* __restrict__ H1TB,
          const float* __restrict__ alw, const float* __restrict__ bew,
          const float* __restrict__ uvw,
          float* __restrict__ H2p, float* __restrict__ Zp, int kslog) {
    const int tid = threadIdx.x;
    const int wn = tid >> 6, lane = tid & 63;
    const int q = lane >> 4, m16 = lane & 15;
    const int ksn = 1 << kslog;
    const int ks = blockIdx.x & (ksn - 1);
    const int mb = blockIdx.x >> kslog;
    const int row0 = mb * 32 + m16, row1 = row0 + 16;
    const float al0 = alw[row0], be0 = bew[row0];
    const float al1 = alw[row1], be1 = bew[row1];
    const int jbase = ks << (13 - kslog);          // ks * (8192/ksn)
    const int chunks = 64 >> kslog;                // (8192/ksn)/32/4

    const unsigned int* Ap0 = Apk + row0 * 256 + (jbase >> 5);
    const unsigned int* Ap1 = Apk + row1 * 256 + (jbase >> 5);
    const float* uvp = uvw + 2 * (jbase + q * 8);
    const unsigned short* Hp = H1TB
        + ((size_t)(wn * 4) * 1024 + (jbase >> 3) + q) * 128 + m16 * 8;

    f32x4 zero4 = {0.f, 0.f, 0.f, 0.f};
    f32x4 acc[4][2];                               // [nt][rg]
#pragma unroll
    for (int nt = 0; nt < 4; ++nt) { acc[nt][0] = zero4; acc[nt][1] = zero4; }
    float z0 = 0.f, z1 = 0.f;

    uint4 aw0 = *(const uint4*)(Ap0);
    uint4 aw1 = *(const uint4*)(Ap1);

    for (int c = 0; c < chunks; ++c) {
        uint4 nx0, nx1;
        if (c + 1 < chunks) {                      // distance-1 A-word prefetch
            nx0 = *(const uint4*)(Ap0 + 4);
            nx1 = *(const uint4*)(Ap1 + 4);
        }
        unsigned wda0[4] = {aw0.x, aw0.y, aw0.z, aw0.w};
        unsigned wda1[4] = {aw1.x, aw1.y, aw1.z, aw1.w};
#pragma unroll
        for (int u = 0; u < 4; ++u) {
            const int t = c * 4 + u;
            const unsigned b0 = (wda0[u] >> (q * 8)) & 0xFFu;   // row0's 8 j-bits
            const unsigned b1 = (wda1[u] >> (q * 8)) & 0xFFu;   // row1's 8 j-bits
            float4 uv0 = *(const float4*)(uvp + t * 64);
            float4 uv1 = *(const float4*)(uvp + t * 64 + 4);
            float4 uv2 = *(const float4*)(uvp + t * 64 + 8);
            float4 uv3 = *(const float4*)(uvp + t * 64 + 12);
            float w0[8], w1[8];
            w0[0] = (b0 & 1u)   ? fmaxf(al0 * uv0.x, be0 * uv0.y) : 0.f;
            w0[1] = (b0 & 2u)   ? fmaxf(al0 * uv0.z, be0 * uv0.w) : 0.f;
            w0[2] = (b0 & 4u)   ? fmaxf(al0 * uv1.x, be0 * uv1.y) : 0.f;
            w0[3] = (b0 & 8u)   ? fmaxf(al0 * uv1.z, be0 * uv1.w) : 0.f;
            w0[4] = (b0 & 16u)  ? fmaxf(al0 * uv2.x, be0 * uv2.y) : 0.f;
            w0[5] = (b0 & 32u)  ? fmaxf(al0 * uv2.z, be0 * uv2.w) : 0.f;
            w0[6] = (b0 & 64u)  ? fmaxf(al0 * uv3.x, be0 * uv3.y) : 0.f;
            w0[7] = (b0 & 128u) ? fmaxf(al0 * uv3.z, be0 * uv3.w) : 0.f;
            w1[0] = (b1 & 1u)   ? fmaxf(al1 * uv0.x, be1 * uv0.y) : 0.f;
            w1[1] = (b1 & 2u)   ? fmaxf(al1 * uv0.z, be1 * uv0.w) : 0.f;
            w1[2] = (b1 & 4u)   ? fmaxf(al1 * uv1.x, be1 * uv1.y) : 0.f;
            w1[3] = (b1 & 8u)   ? fmaxf(al1 * uv1.z, be1 * uv1.w) : 0.f;
            w1[4] = (b1 & 16u)  ? fmaxf(al1 * uv2.x, be1 * uv2.y) : 0.f;
            w1[5] = (b1 & 32u)  ? fmaxf(al1 * uv2.z, be1 * uv2.w) : 0.f;
            w1[6] = (b1 & 64u)  ? fmaxf(al1 * uv3.x, be1 * uv3.y) : 0.f;
            w1[7] = (b1 & 128u) ? fmaxf(al1 * uv3.z, be1 * uv3.w) : 0.f;
            z0 += (w0[0] + w0[1] + w0[2] + w0[3]) + (w0[4] + w0[5] + w0[6] + w0[7]);
            z1 += (w1[0] + w1[1] + w1[2] + w1[3]) + (w1[4] + w1[5] + w1[6] + w1[7]);

            int4 ai0 = {(int)pk2bf(w0[0], w0[1]), (int)pk2bf(w0[2], w0[3]),
                        (int)pk2bf(w0[4], w0[5]), (int)pk2bf(w0[6], w0[7])};
            int4 ai1 = {(int)pk2bf(w1[0], w1[1]), (int)pk2bf(w1[2], w1[3]),
                        (int)pk2bf(w1[4], w1[5]), (int)pk2bf(w1[6], w1[7])};
            s16x8 af0 = __builtin_bit_cast(s16x8, ai0);
            s16x8 af1 = __builtin_bit_cast(s16x8, ai1);
#pragma unroll
            for (int nt = 0; nt < 4; ++nt) {
                s16x8 bf = *(const s16x8*)(Hp + (size_t)nt * 131072 + t * 512);
                acc[nt][0] = __builtin_amdgcn_mfma_f32_16x16x32_bf16(af0, bf, acc[nt][0], 0, 0, 0);
                acc[nt][1] = __builtin_amdgcn_mfma_f32_16x16x32_bf16(af1, bf, acc[nt][1], 0, 0, 0);
            }
        }
        aw0 = nx0; aw1 = nx1;
        Ap0 += 4; Ap1 += 4;
    }

    // Z partial: reduce over q; wn==0 stores (all wn waves compute identical W).
    z0 += __shfl_xor(z0, 16); z0 += __shfl_xor(z0, 32);
    z1 += __shfl_xor(z1, 16); z1 += __shfl_xor(z1, 32);
    if (wn == 0 && q == 0) {
        Zp[ks * NN + row0] = z0;
        Zp[ks * NN + row1] = z1;
    }

    // H2 partial: plain stores, each (row,col) written exactly once per block.
    float* H2s = H2p + (size_t)ks * (NN * HIDD / 1) / (1)  // ks stride = 2M floats
                 ;  // (computed below explicitly)
    H2s = H2p + (size_t)ks * 2097152;
#pragma unroll
    for (int nt = 0; nt < 4; ++nt) {
        const int col = wn * 64 + nt * 16 + m16;
#pragma unroll
        for (int rg = 0; rg < 2; ++rg) {
            const int rowb = mb * 32 + rg * 16 + q * 4;
#pragma unroll
            for (int r = 0; r < 4; ++r)
                H2s[(size_t)(rowb + r) * HIDD + col] = acc[nt][rg][r];
        }
    }
}

// ---- k_out: out = sigmoid((sum_s H2p[s] / sum_s Zp[s]) @ Omega + beta) --------------
__global__ void __launch_bounds__(256)
k_out(const float* __restrict__ H2p, const float* __restrict__ Zp,
      const float* __restrict__ Omega, const float* __restrict__ beta,
      float* __restrict__ out, int ksn) {
    __shared__ float om[HIDD * OUTD];  // 64 KB
    const int tid = threadIdx.x;
    for (int idx = tid; idx < HIDD * OUTD; idx += 256) om[idx] = Omega[idx];
    __syncthreads();
    const int wave = tid >> 6, o = tid & 63;
    const int i0 = blockIdx.x * 32 + wave * 8;
    float accv[8] = {0.f, 0.f, 0.f, 0.f, 0.f, 0.f, 0.f, 0.f};
    for (int s = 0; s < ksn; ++s) {
        const float* Hs = H2p + (size_t)s * 2097152;
        for (int c = 0; c < HIDD; c += 4) {
            const float o0 = om[(c + 0) * OUTD + o];
            const float o1 = om[(c + 1) * OUTD + o];
            const float o2 = om[(c + 2) * OUTD + o];
            const float o3 = om[(c + 3) * OUTD + o];
#pragma unroll
            for (int r = 0; r < 8; ++r) {
                float4 h = *(const float4*)(Hs + (size_t)(i0 + r) * HIDD + c);
                accv[r] = fmaf(h.x, o0, fmaf(h.y, o1, fmaf(h.z, o2, fmaf(h.w, o3, accv[r]))));
            }
        }
    }
    const float bv = beta[o];
#pragma unroll
    for (int r = 0; r < 8; ++r) {
        float z = 0.f;
        for (int s = 0; s < ksn; ++s) z += Zp[s * NN + i0 + r];
        const float logit = accv[r] / z + bv;
        out[(size_t)(i0 + r) * OUTD + o] = 1.0f / (1.0f + expf(-logit));
    }
}

extern "C" void kernel_launch(void* const* d_in, const int* in_sizes, int n_in,
                              void* d_out, int out_size, void* d_ws, size_t ws_size,
                              hipStream_t stream) {
    const float* X     = (const float*)d_in[0];
    const int*   A     = (const int*)d_in[1];
    const float* W1    = (const float*)d_in[2];
    const float* b1    = (const float*)d_in[3];
    const float* avec  = (const float*)d_in[4];
    const float* Omega = (const float*)d_in[5];
    const float* beta  = (const float*)d_in[6];
    float* out = (float*)d_out;
    char* ws = (char*)d_ws;

    // ksn (K-split count) by available workspace:
    //   ksn=4: 46,923,776 B   ksn=2: 30,081,024 B   ksn=1: 21,659,648 B (proven avail)
    int kslog = (ws_size >= 46923776ull) ? 2 : (ws_size >= 30081024ull) ? 1 : 0;
    const int ksn = 1 << kslog;

    size_t off = 0;
    unsigned short* H1TB = (unsigned short*)(ws + off); off += 4194304;
    unsigned int*   Apk  = (unsigned int*)(ws + off);   off += 8388608;
    float* H2p = (float*)(ws + off);
    short* XBhi = (short*)(ws + off);                   // alias: dead before k_attn
    off += (size_t)ksn * 8388608;
    float* Zp  = (float*)(ws + off); off += (size_t)ksn * 32768;
    short* WBhi = (short*)(ws + off); off += 262144;
    short* WBlo = (short*)(ws + off); off += 262144;
    float* alw = (float*)(ws + off); off += 32768;
    float* bew = (float*)(ws + off); off += 32768;
    float* uvw = (float*)(ws + off); off += 65536;

    k_prepX<<<16384, 256, 0, stream>>>(X, XBhi);
    k_prepW<<<512, 256, 0, stream>>>(W1, WBhi, WBlo);
    k_h1<<<512, 256, 0, stream>>>(XBhi, WBhi, WBlo, b1, avec, H1TB, alw, bew, uvw);
    k_packA<<<2048, 256, 0, stream>>>(A, (unsigned long long*)Apk);
    k_attn_ns<<<256 * ksn, 256, 0, stream>>>(Apk, H1TB, alw, bew, uvw, H2p, Zp, kslog);
    k_out<<<256, 256, 0, stream>>>(H2p, Zp, Omega, beta, out, ksn);
}